// Round 10
// baseline (20.161 us; speedup 1.0000x reference)
//
#include <hip/hip_runtime.h>

#define VOC 64
#define CHUNKS 4            // float4 chunks per thread (64 B in, 64 B out)
#define TPB 512

typedef float f32x4 __attribute__((ext_vector_type(4)));

// Single fused dispatch, full-occupancy variant: 1024 blocks x 512 thr =
// 4 blocks/CU x 8 waves = 32 waves/CU (chip max).
//  LUT: lut[v] = (c0*v + a0) % 64, a0 = argmax(W[v,0:64]+b[0:64]),
//       c0 = argmax(W[v,64:128]+b[64:128]); -1 when c0 == 0 (zero row,
//       because edward2 masks the c==0 slice of one_hot_multiply).
//  Load order: W/b (threads 0..255) first, then the streaming input
//  loads -> the LUT compute's waitcnt drains only W/b.
//  Memory policy (R8/R9 counters): PLAIN stores (full-line merge, no RFO,
//  no nt write amplification); NT loads (input never re-read; keeps the
//  stream from evicting W rows / dirty output lines in L2).
//  Input rows are exact one-hots (0.0/1.0): locate the 1.0 with three
//  ballots (presence + 2 bits of sub-index) -- no shuffle in the chain.
__global__ __launch_bounds__(TPB) void flow_fused_kernel(
    const float* __restrict__ in,
    const float* __restrict__ W,
    const float* __restrict__ b,
    float* __restrict__ out,
    int n_chunks)
{
    __shared__ int s_lut[VOC];

    const int tid = threadIdx.x;
    const size_t base = (size_t)blockIdx.x * (TPB * CHUNKS) + tid;
    const f32x4* in4  = reinterpret_cast<const f32x4*>(in);
    f32x4*       out4 = reinterpret_cast<f32x4*>(out);

    // ---- 1. issue LUT source loads FIRST (threads 0..255) ----
    f32x4 wL[4], wS[4], bL[4], bS[4];
    const int v = tid >> 2;          // vocab row (for tid < 256)
    const int q = tid & 3;           // quarter of the row
    if (tid < 256) {
        const f32x4* rowL = reinterpret_cast<const f32x4*>(W + v * 2 * VOC) + q * 4;
        const f32x4* rowS = rowL + (VOC / 4);   // +64 floats
        const f32x4* b4   = reinterpret_cast<const f32x4*>(b);
        #pragma unroll
        for (int k = 0; k < 4; ++k) {
            wL[k] = rowL[k];
            wS[k] = rowS[k];
            bL[k] = b4[q * 4 + k];
            bS[k] = b4[16 + q * 4 + k];
        }
    }

    // ---- 2. issue ALL streaming input loads (nontemporal, stay in flight) ----
    f32x4 vin[CHUNKS];
    #pragma unroll
    for (int i = 0; i < CHUNKS; ++i) {
        size_t c = base + (size_t)i * TPB;
        if (c < (size_t)n_chunks) vin[i] = __builtin_nontemporal_load(&in4[c]);
        else                      vin[i] = (f32x4){0.f, 0.f, 0.f, 0.f};
    }

    // ---- 3. LUT build (waits only on W/b; inputs still airborne) ----
    if (tid < 256) {
        float bvL = -3.402823466e+38f; int biL = 0;
        float bvS = -3.402823466e+38f; int biS = 0;
        #pragma unroll
        for (int k = 0; k < 4; ++k) {
            float x0 = wL[k].x + bL[k].x, x1 = wL[k].y + bL[k].y;
            float x2 = wL[k].z + bL[k].z, x3 = wL[k].w + bL[k].w;
            float y0 = wS[k].x + bS[k].x, y1 = wS[k].y + bS[k].y;
            float y2 = wS[k].z + bS[k].z, y3 = wS[k].w + bS[k].w;
            int ib = q * 16 + k * 4;
            // ascending index + strict > keeps first occurrence (jnp.argmax)
            if (x0 > bvL) { bvL = x0; biL = ib;     }
            if (x1 > bvL) { bvL = x1; biL = ib + 1; }
            if (x2 > bvL) { bvL = x2; biL = ib + 2; }
            if (x3 > bvL) { bvL = x3; biL = ib + 3; }
            if (y0 > bvS) { bvS = y0; biS = ib;     }
            if (y1 > bvS) { bvS = y1; biS = ib + 1; }
            if (y2 > bvS) { bvS = y2; biS = ib + 2; }
            if (y3 > bvS) { bvS = y3; biS = ib + 3; }
        }
        // combine the 4 partials (adjacent lanes): lexicographic max
        #pragma unroll
        for (int off = 1; off < 4; off <<= 1) {
            float ov = __shfl_xor(bvL, off, 4);
            int   oi = __shfl_xor(biL, off, 4);
            if (ov > bvL || (ov == bvL && oi < biL)) { bvL = ov; biL = oi; }
            ov = __shfl_xor(bvS, off, 4);
            oi = __shfl_xor(biS, off, 4);
            if (ov > bvS || (ov == bvS && oi < biS)) { bvS = ov; biS = oi; }
        }
        if (q == 0) s_lut[v] = (biS == 0) ? -1 : (biS * v + biL) & (VOC - 1);
    }
    __syncthreads();

    // ---- 4. stream: locate the 1.0 via 3 ballots, LUT, one-hot write ----
    const int lane = tid & 63;
    const int grp  = lane >> 4;          // 16-lane row group within wave
    const int sub  = tid & 15;           // this lane's quarter of the row
    const int b4i  = sub << 2;

    #pragma unroll
    for (int i = 0; i < CHUNKS; ++i) {
        size_t c = base + (size_t)i * TPB;
        f32x4 x = vin[i];
        int li = -1;                      // local index of the 1.0 (0..3)
        if (x.x > 0.5f) li = 0;
        if (x.y > 0.5f) li = 1;
        if (x.z > 0.5f) li = 2;
        if (x.w > 0.5f) li = 3;
        // presence + two index bits, all as ballots (no shuffle needed)
        unsigned long long mh = __ballot(li >= 0);
        unsigned long long m0 = __ballot(li >= 0 && (li & 1));
        unsigned long long m1 = __ballot(li >= 2);

        unsigned gmh = (unsigned)((mh >> (grp * 16)) & 0xFFFFull);
        int oidx;
        if (gmh == 0) {
            oidx = -1;                    // only possible for tail groups
        } else {
            int wl   = __builtin_ctz(gmh);        // winning sub-lane (0..15)
            int wbit = grp * 16 + wl;             // bit position in 64-bit masks
            int liw  = (int)((m0 >> wbit) & 1ull) | ((int)((m1 >> wbit) & 1ull) << 1);
            int bi   = (wl << 2) | liw;           // vocab index of the input 1.0
            oidx = s_lut[bi];                     // -1 => zero row
        }

        f32x4 vo;
        vo.x = (oidx == b4i)     ? 1.0f : 0.0f;
        vo.y = (oidx == b4i + 1) ? 1.0f : 0.0f;
        vo.z = (oidx == b4i + 2) ? 1.0f : 0.0f;
        vo.w = (oidx == b4i + 3) ? 1.0f : 0.0f;
        if (c < (size_t)n_chunks)
            out4[c] = vo;                 // plain cached store: full-line merge
    }
}

extern "C" void kernel_launch(void* const* d_in, const int* in_sizes, int n_in,
                              void* d_out, int out_size, void* d_ws, size_t ws_size,
                              hipStream_t stream) {
    const float* inputs = (const float*)d_in[0];  // (B, L, 64) f32 one-hot
    const float* W      = (const float*)d_in[1];  // (64, 128) f32
    const float* b      = (const float*)d_in[2];  // (128,) f32
    float* out = (float*)d_out;

    int n_rows   = in_sizes[0] / VOC;             // B*L = 131072
    int n_chunks = n_rows * 16;                   // float4 chunks (mult of 16)

    int per_block = TPB * CHUNKS;
    int blocks = (n_chunks + per_block - 1) / per_block;  // 1024 for B=16,L=8192

    flow_fused_kernel<<<blocks, TPB, 0, stream>>>(inputs, W, b, out, n_chunks);
}

// Round 11
// 17.197 us; speedup vs baseline: 1.1724x; 1.1724x over previous
//
#include <hip/hip_runtime.h>

#define VOC 64
#define CHUNKS 8            // float4 chunks per thread (128 B in, 128 B out)
#define TPB 512

typedef float f32x4 __attribute__((ext_vector_type(4)));

// FINAL: best-measured configuration (round 5, 17.1 us).
// Single fused dispatch.
//  LUT: lut[v] = (c0*v + a0) % 64, a0 = argmax(W[v,0:64]+b[0:64]),
//       c0 = argmax(W[v,64:128]+b[64:128]); -1 when c0 == 0 (zero row,
//       because edward2 masks the c==0 slice of one_hot_multiply).
//  Load order: W/b (threads 0..255) first, then all 8 streaming input
//  loads -> the LUT compute's waitcnt drains only W/b; input stays in
//  flight under the prologue.
//  Input rows are exact one-hots (0.0/1.0): locate the 1.0 with three
//  ballots (presence + 2 bits of sub-index) -- no shuffle in the chain.
//  Session ledger (rounds 1-10): bytes at the 67 MB floor (WRITE_SIZE
//  exactly 33.5 MB, FETCH <= 33.5 MB); store/load cache policy, ILP
//  depth, block size, grid size, occupancy (16 vs 32 waves/CU), and
//  speculative half-row reads all individually falsified as levers.
//  ~17 us = ~10.5 us stream + fixed dispatch overhead.
__global__ __launch_bounds__(TPB) void flow_fused_kernel(
    const float* __restrict__ in,
    const float* __restrict__ W,
    const float* __restrict__ b,
    float* __restrict__ out,
    int n_chunks)
{
    __shared__ int s_lut[VOC];

    const int tid = threadIdx.x;
    const size_t base = (size_t)blockIdx.x * (TPB * CHUNKS) + tid;
    const f32x4* in4  = reinterpret_cast<const f32x4*>(in);
    f32x4*       out4 = reinterpret_cast<f32x4*>(out);

    // ---- 1. issue LUT source loads FIRST (threads 0..255) ----
    f32x4 wL[4], wS[4], bL[4], bS[4];
    const int v = tid >> 2;          // vocab row (for tid < 256)
    const int q = tid & 3;           // quarter of the row
    if (tid < 256) {
        const f32x4* rowL = reinterpret_cast<const f32x4*>(W + v * 2 * VOC) + q * 4;
        const f32x4* rowS = rowL + (VOC / 4);   // +64 floats
        const f32x4* b4   = reinterpret_cast<const f32x4*>(b);
        #pragma unroll
        for (int k = 0; k < 4; ++k) {
            wL[k] = rowL[k];
            wS[k] = rowS[k];
            bL[k] = b4[q * 4 + k];
            bS[k] = b4[16 + q * 4 + k];
        }
    }

    // ---- 2. issue ALL streaming input loads (nontemporal, stay in flight) ----
    f32x4 vin[CHUNKS];
    #pragma unroll
    for (int i = 0; i < CHUNKS; ++i) {
        size_t c = base + (size_t)i * TPB;
        if (c < (size_t)n_chunks) vin[i] = __builtin_nontemporal_load(&in4[c]);
        else                      vin[i] = (f32x4){0.f, 0.f, 0.f, 0.f};
    }

    // ---- 3. LUT build (waits only on W/b; inputs still airborne) ----
    if (tid < 256) {
        float bvL = -3.402823466e+38f; int biL = 0;
        float bvS = -3.402823466e+38f; int biS = 0;
        #pragma unroll
        for (int k = 0; k < 4; ++k) {
            float x0 = wL[k].x + bL[k].x, x1 = wL[k].y + bL[k].y;
            float x2 = wL[k].z + bL[k].z, x3 = wL[k].w + bL[k].w;
            float y0 = wS[k].x + bS[k].x, y1 = wS[k].y + bS[k].y;
            float y2 = wS[k].z + bS[k].z, y3 = wS[k].w + bS[k].w;
            int ib = q * 16 + k * 4;
            // ascending index + strict > keeps first occurrence (jnp.argmax)
            if (x0 > bvL) { bvL = x0; biL = ib;     }
            if (x1 > bvL) { bvL = x1; biL = ib + 1; }
            if (x2 > bvL) { bvL = x2; biL = ib + 2; }
            if (x3 > bvL) { bvL = x3; biL = ib + 3; }
            if (y0 > bvS) { bvS = y0; biS = ib;     }
            if (y1 > bvS) { bvS = y1; biS = ib + 1; }
            if (y2 > bvS) { bvS = y2; biS = ib + 2; }
            if (y3 > bvS) { bvS = y3; biS = ib + 3; }
        }
        // combine the 4 partials (adjacent lanes): lexicographic max
        #pragma unroll
        for (int off = 1; off < 4; off <<= 1) {
            float ov = __shfl_xor(bvL, off, 4);
            int   oi = __shfl_xor(biL, off, 4);
            if (ov > bvL || (ov == bvL && oi < biL)) { bvL = ov; biL = oi; }
            ov = __shfl_xor(bvS, off, 4);
            oi = __shfl_xor(biS, off, 4);
            if (ov > bvS || (ov == bvS && oi < biS)) { bvS = ov; biS = oi; }
        }
        if (q == 0) s_lut[v] = (biS == 0) ? -1 : (biS * v + biL) & (VOC - 1);
    }
    __syncthreads();

    // ---- 4. stream: locate the 1.0 via 3 ballots, LUT, one-hot write ----
    const int lane = tid & 63;
    const int grp  = lane >> 4;          // 16-lane row group within wave
    const int sub  = tid & 15;           // this lane's quarter of the row
    const int b4i  = sub << 2;

    #pragma unroll
    for (int i = 0; i < CHUNKS; ++i) {
        size_t c = base + (size_t)i * TPB;
        f32x4 x = vin[i];
        int li = -1;                      // local index of the 1.0 (0..3)
        if (x.x > 0.5f) li = 0;
        if (x.y > 0.5f) li = 1;
        if (x.z > 0.5f) li = 2;
        if (x.w > 0.5f) li = 3;
        // presence + two index bits, all as ballots (no shuffle needed)
        unsigned long long mh = __ballot(li >= 0);
        unsigned long long m0 = __ballot(li >= 0 && (li & 1));
        unsigned long long m1 = __ballot(li >= 2);

        unsigned gmh = (unsigned)((mh >> (grp * 16)) & 0xFFFFull);
        int oidx;
        if (gmh == 0) {
            oidx = -1;                    // only possible for tail groups
        } else {
            int wl   = __builtin_ctz(gmh);        // winning sub-lane (0..15)
            int wbit = grp * 16 + wl;             // bit position in 64-bit masks
            int liw  = (int)((m0 >> wbit) & 1ull) | ((int)((m1 >> wbit) & 1ull) << 1);
            int bi   = (wl << 2) | liw;           // vocab index of the input 1.0
            oidx = s_lut[bi];                     // -1 => zero row
        }

        f32x4 vo;
        vo.x = (oidx == b4i)     ? 1.0f : 0.0f;
        vo.y = (oidx == b4i + 1) ? 1.0f : 0.0f;
        vo.z = (oidx == b4i + 2) ? 1.0f : 0.0f;
        vo.w = (oidx == b4i + 3) ? 1.0f : 0.0f;
        if (c < (size_t)n_chunks)
            __builtin_nontemporal_store(vo, &out4[c]);
    }
}

extern "C" void kernel_launch(void* const* d_in, const int* in_sizes, int n_in,
                              void* d_out, int out_size, void* d_ws, size_t ws_size,
                              hipStream_t stream) {
    const float* inputs = (const float*)d_in[0];  // (B, L, 64) f32 one-hot
    const float* W      = (const float*)d_in[1];  // (64, 128) f32
    const float* b      = (const float*)d_in[2];  // (128,) f32
    float* out = (float*)d_out;

    int n_rows   = in_sizes[0] / VOC;             // B*L = 131072
    int n_chunks = n_rows * 16;                   // float4 chunks (mult of 16)

    int per_block = TPB * CHUNKS;
    int blocks = (n_chunks + per_block - 1) / per_block;  // 512 for B=16,L=8192

    flow_fused_kernel<<<blocks, TPB, 0, stream>>>(inputs, W, b, out, n_chunks);
}